// Round 8
// baseline (4729.116 us; speedup 1.0000x reference)
//
#include <hip/hip_runtime.h>
#include <stdint.h>
#include <string.h>
#include <math.h>

// DCRNN forward on MI355X. Runtime dtype detection (fp32 vs bf16) via enc0_bg==ones.
// P1..P4 precomputed bf16 (Pbig); gconv = GEMM1 (X@W -> VT scatter) + GEMM2 (P@V, K=2048,
// fused epilogue). gl16 direct-to-LDS staging, XOR-swizzled (slot=r*CH+(c^(r&7))).
// K-loop double-buffered, fine-grained s_waitcnt vmcnt(N) + raw s_barrier (AITER pattern).
// Tile shapes chosen to minimize LLC traffic (A*ntiles + B*mtiles): gate GEMM2 reads
// Pbig exactly once (BM=128,BN=128); cand GEMM2 likewise (BM=128,BN=64). GEMM2 grids
// 1-D, bz=blk%32 -> same batch lands on same XCD. Persistent X buffers maintained by
// epilogues (no pack kernels in the RNN loop).

using bfrag = __attribute__((__ext_vector_type__(8))) short;
using accv  = __attribute__((__ext_vector_type__(4))) float;

#define DEVI static __device__ __forceinline__

DEVI float bf2f(short x) {
  union { unsigned u; float f; } v; v.u = ((unsigned)(unsigned short)x) << 16; return v.f;
}
DEVI short f2bf(float f) {
  union { float f; unsigned u; } v; v.f = f;
  unsigned r = v.u + 0x7FFFu + ((v.u >> 16) & 1u);
  return (short)(r >> 16);
}
DEVI float ldx(const void* p, long i, int f32) {
  return f32 ? ((const float*)p)[i] : bf2f(((const short*)p)[i]);
}
DEVI void gl16(const short* g, short* l) {  // 16B direct global->LDS (dest = base + lane*16)
  __builtin_amdgcn_global_load_lds(
      (const __attribute__((address_space(1))) void*)g,
      (__attribute__((address_space(3))) void*)l, 16, 0, 0);
}

struct GP {
  const short* A;  long sA;  int lda;    // A: (M x K) row-major per batch (bf16 internal)
  const short* BT; long sBT; int ldbt;   // B transposed: (N x K) row-major per batch
  int K;
  short* C; long sC; int ldc;            // EPI 0/1 normal store
  short* CT;                             // EPI 2: plain transpose store; EPI 3: VT scatter
  const void* bias;                      // EXTERNAL bias (dtype per flag)
  const short* V0;                       // VT base (identity term) for EPI 4/5
  const int* flg;
  int outDim, oshift;
  int mtiles;                            // SWZ=1: M-tiles per batch
  const float* h; float* hw; const float* u;
  short* xc; int inpOff;                 // EPI4: Xc target (r*h), state col offset
  // EPI5 persistent-X maintenance:
  short* xgs; int xgsOff;                // Xg state cols target
  short* xch;                            // Xc base (hist cols partner, enc cell0)
  short* nxg; short* nxc;                // next-layer inp cols targets
  const void* hsrc; long hoff;           // hist source for next timestep (enc cell0)
};

// BM x BN tile, BK k-slab, THR threads, double-buffered LDS.
// SWZ=0: blockIdx.{x,y,z} = (mt, nt, bz). SWZ=1: 1-D grid, bz=blk%32, tile=blk/32,
//        mt=tile%mtiles, nt=tile/mtiles (XCD locality: same batch -> same blk%8).
// EPI: 0 plain; 1 bias+relu; 2 +transposed copy; 3 VT scatter (BM=128 only);
//      4 gate epilogue; 5 cand epilogue.
template<int EPI, int BM, int BN, int BK, int THR, int SWZ>
__global__ __launch_bounds__(THR)
void gemm_k(GP p) {
  constexpr int W    = THR / 64;
  constexpr int WROW = BM / 32;
  constexpr int WCOL = (W / WROW < 1) ? 1 : W / WROW;
  constexpr int NT   = BN / (16 * WCOL);
  constexpr int CH   = BK / 8;                  // 16B chunks per row
  constexpr int AI   = (BM * CH) / THR;         // A chunks per thread per k-slab
  constexpr int BI   = (BN * CH) / THR;
  constexpr int LD   = AI + BI;                 // gl16 per wave per k-iter
  constexpr int TB   = (BM + BN) * BK;          // one buffer, shorts
  __shared__ __align__(16) short lds[2*TB];
  const int tid  = threadIdx.x;
  const int w    = tid >> 6;
  const int lane = tid & 63;
  const int quad = lane >> 4, l16 = lane & 15;
  const int rowW = (w % WROW) * 32;
  const int colW = (w / WROW) * (NT * 16);
  int m0, n0, bz;
  if constexpr (SWZ == 1) {
    const int blk = blockIdx.x;
    bz = blk & 31;
    const int tile = blk >> 5;
    m0 = (tile % p.mtiles) * BM;
    n0 = (tile / p.mtiles) * BN;
  } else {
    m0 = blockIdx.x * BM; n0 = blockIdx.y * BN; bz = blockIdx.z;
  }

  const short* Ab = p.A  + (long)bz * p.sA + m0 * (long)p.lda;
  const short* Bb = p.BT + (long)bz * p.sBT + n0 * (long)p.ldbt;

  accv acc[2][NT];
#pragma unroll
  for (int i = 0; i < 2; i++)
#pragma unroll
    for (int j = 0; j < NT; j++) { accv z = {0.f,0.f,0.f,0.f}; acc[i][j] = z; }

  // per-lane swizzled staging coords (slot s -> row r = s/CH, chunk c = (s%CH)^(r&7))
  const short* asrc[AI]; int aoff[AI];
#pragma unroll
  for (int i = 0; i < AI; i++) {
    const int s = (w*AI + i)*64 + lane;
    const int r = s / CH, c = (s % CH) ^ (r & 7);
    asrc[i] = Ab + (long)r * p.lda + c*8;
    aoff[i] = (w*AI + i)*512;
  }
  const short* bsrc[BI]; int boff[BI];
#pragma unroll
  for (int i = 0; i < BI; i++) {
    const int s = (w*BI + i)*64 + lane;
    const int r = s / CH, c = (s % CH) ^ (r & 7);
    bsrc[i] = Bb + (long)r * p.ldbt + c*8;
    boff[i] = BM*BK + (w*BI + i)*512;
  }

  const int nIter = p.K / BK;
  // prologue: issue slab 0 into buffer 0
#pragma unroll
  for (int i = 0; i < AI; i++) gl16(asrc[i], &lds[aoff[i]]);
#pragma unroll
  for (int i = 0; i < BI; i++) gl16(bsrc[i], &lds[boff[i]]);

  for (int it = 0; it < nIter; ++it) {
    const int bufO = (it & 1) * TB;
    if (it + 1 < nIter) {
      const int nxt = ((it + 1) & 1) * TB;
      const int kk = (it + 1) * BK;
#pragma unroll
      for (int i = 0; i < AI; i++) gl16(asrc[i] + kk, &lds[nxt + aoff[i]]);
#pragma unroll
      for (int i = 0; i < BI; i++) gl16(bsrc[i] + kk, &lds[nxt + boff[i]]);
      __builtin_amdgcn_s_waitcnt(0xF70 | LD);   // wait slab it; keep it+1 in flight
    } else {
      __builtin_amdgcn_s_waitcnt(0xF70);        // vmcnt(0)
    }
    asm volatile("s_barrier" ::: "memory");
#pragma unroll
    for (int ks = 0; ks < BK; ks += 32) {
      const int ch = (ks >> 3) + quad;          // 16B chunk index within row
      bfrag fa[2];
#pragma unroll
      for (int rt = 0; rt < 2; rt++) {
        const int ar = rowW + rt*16 + l16;
        fa[rt] = *(const bfrag*)&lds[bufO + (ar*CH + (ch ^ (ar & 7))) * 8];
      }
#pragma unroll
      for (int nt = 0; nt < NT; nt++) {
        const int br = colW + nt*16 + l16;
        bfrag fb = *(const bfrag*)&lds[bufO + BM*BK + (br*CH + (ch ^ (br & 7))) * 8];
        acc[0][nt] = __builtin_amdgcn_mfma_f32_16x16x32_bf16(fa[0], fb, acc[0][nt], 0, 0, 0);
        acc[1][nt] = __builtin_amdgcn_mfma_f32_16x16x32_bf16(fa[1], fb, acc[1][nt], 0, 0, 0);
      }
    }
    asm volatile("s_barrier" ::: "memory");
  }

  int f32 = 0;
  if constexpr (EPI == 1 || EPI == 4 || EPI == 5) f32 = *p.flg;

  if constexpr (EPI == 0 || EPI == 1 || EPI == 2) {
#pragma unroll
    for (int rt = 0; rt < 2; rt++) {
      const int rbase = m0 + rowW + rt*16 + quad*4;
#pragma unroll
      for (int nt = 0; nt < NT; nt++) {
        const int cc = n0 + colW + nt*16 + l16;
#pragma unroll
        for (int e = 0; e < 4; e++) {
          float val = acc[rt][nt][e];
          if constexpr (EPI == 1) { val += ldx(p.bias, cc, f32); val = val > 0.f ? val : 0.f; }
          p.C[(long)bz * p.sC + (long)(rbase + e) * p.ldc + cc] = f2bf(val);
        }
      }
    }
  }
  if constexpr (EPI == 2 || EPI == 3) {
    // regs -> LDS transposed tile (BN cols x BM rows, stride 136); BM=128 only
    __syncthreads();
#pragma unroll
    for (int rt = 0; rt < 2; rt++)
#pragma unroll
      for (int nt = 0; nt < NT; nt++)
#pragma unroll
        for (int e = 0; e < 4; e++)
          lds[(colW + nt*16 + l16)*136 + (rowW + rt*16 + quad*4 + e)] = f2bf(acc[rt][nt][e]);
    __syncthreads();
    const int c = tid >> 2, seg = tid & 3;     // c in [0,THR/4) == [0,BN) when THR==4*BN
    const int cG = n0 + c;
    const short* sp = &lds[c*136 + seg*32];
    long dst;
    if constexpr (EPI == 3) {
      const int m  = cG >> p.oshift;
      const int o  = cG & (p.outDim - 1);
      const int bb = m0 >> 9;
      dst = ((long)((bb * p.outDim + o) * 5 + m) << 9) + (m0 & 511) + seg*32;
    } else {
      dst = (((long)bz << 9) + cG) * 512 + m0 + seg*32;
    }
    short* dp = p.CT + dst;
    *(bfrag*)(dp)      = *(const bfrag*)(sp);
    *(bfrag*)(dp + 8)  = *(const bfrag*)(sp + 8);
    *(bfrag*)(dp + 16) = *(const bfrag*)(sp + 16);
    *(bfrag*)(dp + 24) = *(const bfrag*)(sp + 24);
  }
  if constexpr (EPI == 4) {  // gate: sigmoid; o<64 -> Xc = r*h ; o>=64 -> u
#pragma unroll
    for (int rt = 0; rt < 2; rt++) {
      const int nb = m0 + rowW + rt*16 + quad*4;
#pragma unroll
      for (int nt = 0; nt < NT; nt++) {
        const int o = n0 + colW + nt*16 + l16;
        const float bv = ldx(p.bias, o, f32);
#pragma unroll
        for (int e = 0; e < 4; e++) {
          const int nn = nb + e;
          float val = acc[rt][nt][e] + bv +
                      bf2f(p.V0[(long)(bz * p.outDim + o) * 2560 + nn]);
          const float s = 1.f / (1.f + __expf(-val));
          const long bn = ((long)bz << 9) + nn;
          if (o < 64) p.xc[bn*128 + p.inpOff + o] = f2bf(s * p.h[(bn << 6) + o]);
          else        p.hw[(bn << 6) + (o - 64)] = s;
        }
      }
    }
  }
  if constexpr (EPI == 5) {  // cand: tanh; h = u*h + (1-u)*c; maintain persistent X bufs
#pragma unroll
    for (int rt = 0; rt < 2; rt++) {
      const int nb = m0 + rowW + rt*16 + quad*4;
#pragma unroll
      for (int nt = 0; nt < NT; nt++) {
        const int o = n0 + colW + nt*16 + l16;
        const float bv = ldx(p.bias, o, f32);
#pragma unroll
        for (int e = 0; e < 4; e++) {
          const int nn = nb + e;
          float val = acc[rt][nt][e] + bv +
                      bf2f(p.V0[(long)(bz * p.outDim + o) * 2560 + nn]);
          const float cth = tanhf(val);
          const long bn = ((long)bz << 9) + nn;
          const long idx = bn*64 + o;
          const float uo = p.u[idx];
          const float hn = uo * p.h[idx] + (1.f - uo) * cth;
          p.hw[idx] = hn;
          const short hb = f2bf(hn);
          if (p.xgs) p.xgs[bn*128 + p.xgsOff + o] = hb;
          if (p.nxg) { p.nxg[bn*128 + o] = hb; p.nxc[bn*128 + o] = hb; }
          if (p.hsrc != nullptr && o < 2) {
            const short hv = f2bf(ldx(p.hsrc, p.hoff + (long)bz*12288 + (long)nn*2 + o, f32));
            p.xgs[bn*128 + o] = hv;
            p.xch[bn*128 + o] = hv;
          }
        }
      }
    }
  }
}

// ---- small kernels ----

__global__ void detect_k(const short* bg0, int* flag) {
  if (threadIdx.x == 0 && blockIdx.x == 0)
    *flag = (bg0[0] == (short)0x3F80) ? 0 : 1;  // bf16 ones -> 0x3F80; fp32 ones low short = 0
}

__global__ void rowsum_inv(const void* adj, const int* flg, float* rsi) {
  const int f32 = *flg;
  const int wid  = (blockIdx.x * 256 + threadIdx.x) >> 6;  // row index b*512+i
  const int lane = threadIdx.x & 63;
  const long base = (long)wid * 512;
  float s = 0.f;
  for (int j = lane; j < 512; j += 64) s += ldx(adj, base + j, f32);
  for (int off = 32; off > 0; off >>= 1) s += __shfl_down(s, off, 64);
  if (lane == 0) rsi[wid] = 1.f / (1.f + s);
}

__global__ void colsum_inv(const void* adj, const int* flg, float* csi) {
  const int f32 = *flg;
  const int i = blockIdx.x * 256 + threadIdx.x;  // b*512+col
  const int b = i >> 9, col = i & 511;
  const long base = (long)b * 262144 + col;
  float s = 1.f;
  for (int j = 0; j < 512; j++) s += ldx(adj, base + (long)j * 512, f32);
  csi[i] = 1.f / s;
}

// A1 -> Pbig block0 (ld 2048); A1T, A2 (512x512, ld 512) per batch
__global__ __launch_bounds__(256)
void build_a(const void* adj, const int* flg, const float* rsi, const float* csi,
             short* Pbig, short* A1T, short* A2) {
  const int f32 = *flg;
  __shared__ __align__(16) float t[64 * 65];
  const int b = blockIdx.z, ti = blockIdx.x, tj = blockIdx.y;
  const int tid = threadIdx.x;
  const int r = tid >> 2, cs = (tid & 3) * 16;
  const long base = (long)b * 262144 + (long)(ti*64 + r) * 512 + tj*64 + cs;
#pragma unroll
  for (int j = 0; j < 16; j++) t[r*65 + cs + j] = ldx(adj, base + j, f32);
  __syncthreads();
  {
    const int gi = ti*64 + r;
    const float inv = rsi[b*512 + gi];
    short o[16];
#pragma unroll
    for (int j = 0; j < 16; j++) {
      const int gj = tj*64 + cs + j;
      o[j] = f2bf((t[r*65 + cs + j] + (gi == gj ? 1.f : 0.f)) * inv);
    }
    short* dp = Pbig + ((long)(b*512 + gi) << 11) + tj*64 + cs;
    bfrag v0 = {o[0],o[1],o[2],o[3],o[4],o[5],o[6],o[7]};
    bfrag v1 = {o[8],o[9],o[10],o[11],o[12],o[13],o[14],o[15]};
    *(bfrag*)dp = v0; *(bfrag*)(dp + 8) = v1;
  }
  {
    const int y = tj*64 + r;  // output row for A1T and A2
    const float invc = csi[b*512 + y];
    short o1[16], o2[16];
#pragma unroll
    for (int j = 0; j < 16; j++) {
      const int x = ti*64 + cs + j;
      const float av = t[(cs + j)*65 + r];     // adj[x][y]
      const float d = (x == y) ? 1.f : 0.f;
      o1[j] = f2bf((av + d) * rsi[b*512 + x]);  // A1T[y][x] = A1[x][y]
      o2[j] = f2bf((av + d) * invc);            // A2[y][x]  = (adj[x][y]+d)/cs[y]
    }
    short* d1 = A1T + ((long)(b*512 + y) << 9) + ti*64 + cs;
    short* d2 = A2  + ((long)(b*512 + y) << 9) + ti*64 + cs;
    bfrag a0 = {o1[0],o1[1],o1[2],o1[3],o1[4],o1[5],o1[6],o1[7]};
    bfrag a1 = {o1[8],o1[9],o1[10],o1[11],o1[12],o1[13],o1[14],o1[15]};
    bfrag b0 = {o2[0],o2[1],o2[2],o2[3],o2[4],o2[5],o2[6],o2[7]};
    bfrag b1 = {o2[8],o2[9],o2[10],o2[11],o2[12],o2[13],o2[14],o2[15]};
    *(bfrag*)d1 = a0; *(bfrag*)(d1 + 8) = a1;
    *(bfrag*)d2 = b0; *(bfrag*)(d2 + 8) = b1;
  }
}

// folded + transposed gconv weights: WT[(m*out+o)*128 + feat]; W row index = feat*5 + m
__global__ void build_wcat(const void* W, const int* flg, short* WT, int f, int out) {
  const int f32 = *flg;
  const int i = blockIdx.x * 256 + threadIdx.x;
  if (i >= 5 * out * 128) return;
  const int feat = i & 127;
  const int mo = i >> 7;
  const int m = mo / out;
  const int o = mo - m * out;
  float v = 0.f;
  if (feat < f) {
    const long base = (long)feat * 5 * out;
    const float w0 = ldx(W, base + 0*out + o, f32);
    const float w1 = ldx(W, base + 1*out + o, f32);
    const float w2 = ldx(W, base + 2*out + o, f32);
    const float w3 = ldx(W, base + 3*out + o, f32);
    const float w4 = ldx(W, base + 4*out + o, f32);
    v = (m == 0) ? (w0 - w2) : (m == 1) ? (w1 - w4) : (m == 2) ? 2.f*w2
      : (m == 3) ? w3 : 2.f*w4;
  }
  WT[(long)mo * 128 + feat] = f2bf(v);
}

__global__ void build_fc1T(const void* W, const int* flg, short* WT) {
  const int f32 = *flg;
  const int i = blockIdx.x * 256 + threadIdx.x;  // 256*128
  const int o = i >> 7, k = i & 127;
  WT[i] = (k < 96) ? f2bf(ldx(W, (long)k*256 + o, f32)) : (short)0;
}
__global__ void build_fc2T(const void* W, const int* flg, short* WT) {
  const int f32 = *flg;
  const int i = blockIdx.x * 256 + threadIdx.x;  // 64*256
  const int o = i >> 8, k = i & 255;
  WT[i] = f2bf(ldx(W, (long)k*64 + o, f32));
}
__global__ void pack_hid(const void* hd, const int* flg, short* hp) {
  const int f32 = *flg;
  const int i = blockIdx.x * 256 + threadIdx.x;  // 16384*128
  const int row = i >> 7, k = i & 127;
  hp[i] = (k < 96) ? f2bf(ldx(hd, (long)row*96 + k, f32)) : (short)0;
}

// seed encoder t=0 hist cols into Xg0/Xc0
__global__ void seed_hist(const void* hist, const int* flg, short* Xg0, short* Xc0) {
  const int f32 = *flg;
  const int i = blockIdx.x * 256 + threadIdx.x;  // 32768
  const int row = i >> 1, c = i & 1;
  const short v = f2bf(ldx(hist, (long)(row >> 9)*12288 + (long)(row & 511)*2 + c, f32));
  Xg0[(long)row*128 + c] = v;
  Xc0[(long)row*128 + c] = v;
}

// enc->dec boundary: h += his; rewrite Xg0 (dec layout: col0=0, state cols 1..64) and
// Xg1 state cols 64..127; zero Xc0 col0.
__global__ void his_add(float* h0, float* h1, const short* his,
                        short* Xg0, short* Xc0, short* Xg1) {
  const int i = blockIdx.x * 256 + threadIdx.x;  // 1048576
  const int row = i >> 6, o = i & 63;
  const float v = bf2f(his[i]);
  const float a = h0[i] + v, b = h1[i] + v;
  h0[i] = a; h1[i] = b;
  Xg0[(long)row*128 + 1 + o]  = f2bf(a);
  Xg1[(long)row*128 + 64 + o] = f2bf(b);
  if (o == 0) { Xg0[(long)row*128] = 0; Xc0[(long)row*128] = 0; }
}

__global__ void proj_k(const float* h1, const void* pw, const void* pb, const int* flg,
                       void* dout, short* Xg0, short* Xc0, int t) {
  const int f32 = *flg;
  const int i = blockIdx.x * 256 + threadIdx.x;  // 16384
  const float* hr = h1 + (long)i * 64;
  float s = ldx(pb, 0, f32);
  for (int j = 0; j < 64; j++) s += hr[j] * ldx(pw, j, f32);
  if (f32) ((float*)dout)[i*12 + t] = s;
  else     ((short*)dout)[i*12 + t] = f2bf(s);
  const short v = f2bf(s);
  Xg0[(long)i*128] = v;
  Xc0[(long)i*128] = v;
}

extern "C" void kernel_launch(void* const* d_in, const int* in_sizes, int n_in,
                              void* d_out, int out_size, void* d_ws, size_t ws_size,
                              hipStream_t stream) {
  (void)in_sizes; (void)n_in; (void)out_size;
  const void* hist   = d_in[0];
  const void* hidden = d_in[1];
  const void* adj    = d_in[2];
  const void* Wg[4] = {d_in[3], d_in[7],  d_in[11], d_in[15]};
  const void* bg[4] = {d_in[4], d_in[8],  d_in[12], d_in[16]};
  const void* Wc[4] = {d_in[5], d_in[9],  d_in[13], d_in[17]};
  const void* bc[4] = {d_in[6], d_in[10], d_in[14], d_in[18]};
  const void* projW = d_in[19];
  const void* projb = d_in[20];
  const void* fc1W  = d_in[21];
  const void* fc1b  = d_in[22];
  const void* fc2W  = d_in[23];
  const void* fc2b  = d_in[24];

  // ---- workspace layout: persistent + phase-union (lifetimes disjoint) ----
  char* wp = (char*)d_ws;
  auto alloc = [&](size_t bytes) { char* r = wp; wp += (bytes + 255) & ~(size_t)255; return r; };
  short* Pbig = (short*)alloc(32ull*512*2048*2);   // [A1 | A1^2 | A2A1 | A2^2A1], ld 2048
  float* ub   = (float*)alloc(16384ull*64*4);
  float* h0   = (float*)alloc(16384ull*64*4);
  float* h1   = (float*)alloc(16384ull*64*4);
  short* hisb = (short*)alloc(16384ull*64*2);
  short* wctg[4]; for (int i = 0; i < 4; i++) wctg[i] = (short*)alloc(640*128*2);
  short* wctc[4]; for (int i = 0; i < 4; i++) wctc[i] = (short*)alloc(320*128*2);
  float* rsi = (float*)alloc(16384*4);
  float* csi = (float*)alloc(16384*4);
  int*   flg = (int*)alloc(256);
  // phase-union region (phase lifetimes disjoint)
  char* ubase = wp;
  short* hidp = (short*)ubase;                         // phase0: 4,194,304 B
  short* mid  = (short*)(ubase + 4194304);             //          8,388,608 B
  short* fc1T = (short*)(ubase + 4194304 + 8388608);   //          65,536 B
  short* fc2T = (short*)(ubase + 4194304 + 8388608 + 65536);
  short* A1T  = (short*)ubase;                         // phase1: 16,777,216 B each
  short* A2   = (short*)(ubase + 16777216);
  short* P3T  = (short*)(ubase + 33554432);
  short* VTg  = (short*)ubase;                         // phase2: 20,971,520 B
  short* VTc  = (short*)(ubase + 20971520);            //         10,485,760 B
  short* Xg0  = (short*)(ubase + 31457280);            //          4,194,304 B each
  short* Xc0  = (short*)(ubase + 35651584);
  short* Xg1  = (short*)(ubase + 39845888);
  short* Xc1  = (short*)(ubase + 44040192);
  const size_t need = (size_t)(ubase - (char*)d_ws) + 48234496 + 2097152;
  if (ws_size < need) return;  // d_out stays zero: finite-absmax diagnostic signature

  detect_k<<<1, 64, 0, stream>>>((const short*)bg[0], flg);
  hipMemsetAsync(h0, 0, 16384ull*64*4, stream);
  hipMemsetAsync(h1, 0, 16384ull*64*4, stream);

  // ---- phase 0: weight prep + fc_his ----
  const int fdim[4] = {66, 128, 65, 128};  // enc0, enc1, dec0, dec1
  for (int i = 0; i < 4; i++) {
    build_wcat<<<320, 256, 0, stream>>>(Wg[i], flg, wctg[i], fdim[i], 128);
    build_wcat<<<160, 256, 0, stream>>>(Wc[i], flg, wctc[i], fdim[i], 64);
  }
  build_fc1T<<<128, 256, 0, stream>>>(fc1W, flg, fc1T);
  build_fc2T<<<64, 256, 0, stream>>>(fc2W, flg, fc2T);
  pack_hid<<<8192, 256, 0, stream>>>(hidden, flg, hidp);

  GP p;
  // fc_his: his = relu(relu(hid @ fc1 + b1) @ fc2 + b2)
  p = GP{}; p.A = hidp; p.lda = 128; p.BT = fc1T; p.ldbt = 128; p.K = 128;
  p.C = mid; p.ldc = 256; p.bias = fc1b; p.flg = flg;
  gemm_k<1,128,64,64,256,0><<<dim3(128, 4, 1), 256, 0, stream>>>(p);
  p = GP{}; p.A = mid; p.lda = 256; p.BT = fc2T; p.ldbt = 256; p.K = 256;
  p.C = hisb; p.ldc = 64; p.bias = fc2b; p.flg = flg;
  gemm_k<1,128,64,64,256,0><<<dim3(128, 1, 1), 256, 0, stream>>>(p);

  // ---- phase 1: diffusion matrices ----
  rowsum_inv<<<4096, 256, 0, stream>>>(adj, flg, rsi);
  colsum_inv<<<64, 256, 0, stream>>>(adj, flg, csi);
  build_a<<<dim3(8, 8, 32), 256, 0, stream>>>(adj, flg, rsi, csi, Pbig, A1T, A2);

  p = GP{}; p.A = Pbig; p.sA = 512*2048; p.lda = 2048;    // P2 = A1 @ A1
  p.BT = A1T; p.sBT = 512*512; p.ldbt = 512; p.K = 512;
  p.C = Pbig + 512; p.sC = 512*2048; p.ldc = 2048; p.flg = flg;
  gemm_k<0,128,64,64,256,0><<<dim3(4, 8, 32), 256, 0, stream>>>(p);
  p = GP{}; p.A = A2; p.sA = 512*512; p.lda = 512;        // P3 = A2 @ A1 (+ P3T)
  p.BT = A1T; p.sBT = 512*512; p.ldbt = 512; p.K = 512;
  p.C = Pbig + 1024; p.sC = 512*2048; p.ldc = 2048; p.CT = P3T; p.flg = flg;
  gemm_k<2,128,64,64,256,0><<<dim3(4, 8, 32), 256, 0, stream>>>(p);
  p = GP{}; p.A = A2; p.sA = 512*512; p.lda = 512;        // P4 = A2 @ P3
  p.BT = P3T; p.sBT = 512*512; p.ldbt = 512; p.K = 512;
  p.C = Pbig + 1536; p.sC = 512*2048; p.ldc = 2048; p.flg = flg;
  gemm_k<0,128,64,64,256,0><<<dim3(4, 8, 32), 256, 0, stream>>>(p);

  // ---- phase 2: RNN (persistent X buffers) ----
  hipMemsetAsync(Xg0, 0, 4ull*4194304, stream);  // Xg0,Xc0,Xg1,Xc1 contiguous
  seed_hist<<<128, 256, 0, stream>>>(hist, flg, Xg0, Xc0);

  // cell: wi weight idx, inpOff state col, hstate; EPI5 maintenance params
  auto run_cell = [&](int wi, int inpOff, float* hstate, short* XgL, short* XcL,
                      short* nxg, short* nxc, const void* hsrc, long hoff) {
    GP q;
    // GEMM1 gate: XgL(16384x128) @ WcatT -> VTg scatter (BN=128: A read 5x not 10x)
    q = GP{}; q.A = XgL; q.lda = 128; q.BT = wctg[wi]; q.ldbt = 128; q.K = 128;
    q.CT = VTg; q.outDim = 128; q.oshift = 7; q.flg = flg;
    gemm_k<3,128,128,64,512,0><<<dim3(128, 5, 1), 512, 0, stream>>>(q);
    // GEMM2 gate: Pbig @ U (K=2048) -> sigmoid -> (r*h into XcL, u)
    // BM=128,BN=128: Pbig read exactly once (64 MB); 128 blocks, XCD swizzle
    q = GP{}; q.A = Pbig; q.sA = 512*2048; q.lda = 2048;
    q.BT = VTg + 512; q.sBT = 128*2560; q.ldbt = 2560; q.K = 2048;
    q.V0 = VTg; q.outDim = 128; q.bias = bg[wi]; q.flg = flg; q.mtiles = 4;
    q.h = hstate; q.hw = ub; q.xc = XcL; q.inpOff = inpOff;
    gemm_k<4,128,128,64,512,1><<<dim3(128, 1, 1), 512, 0, stream>>>(q);
    // GEMM1 cand
    q = GP{}; q.A = XcL; q.lda = 128; q.BT = wctc[wi]; q.ldbt = 128; q.K = 128;
    q.CT = VTc; q.outDim = 64; q.oshift = 6; q.flg = flg;
    gemm_k<3,128,64,64,256,0><<<dim3(128, 5, 1), 256, 0, stream>>>(q);
    // GEMM2 cand: tanh + h update + persistent-X maintenance
    // BM=128,BN=64: Pbig read exactly once; 128 blocks, XCD swizzle
    q = GP{}; q.A = Pbig; q.sA = 512*2048; q.lda = 2048;
    q.BT = VTc + 512; q.sBT = 64*2560; q.ldbt = 2560; q.K = 2048;
    q.V0 = VTc; q.outDim = 64; q.bias = bc[wi]; q.flg = flg; q.mtiles = 4;
    q.h = hstate; q.hw = hstate; q.u = ub;
    q.xgs = XgL; q.xgsOff = inpOff; q.xch = XcL;
    q.nxg = nxg; q.nxc = nxc; q.hsrc = hsrc; q.hoff = hoff;
    gemm_k<5,128,64,64,256,1><<<dim3(128, 1, 1), 256, 0, stream>>>(q);
  };

  // encoder
  for (int t = 0; t < 12; t++) {
    run_cell(0, 2, h0, Xg0, Xc0, Xg1, Xc1,
             (t < 11) ? hist : nullptr, (long)(t + 1) * 1024);
    run_cell(1, 64, h1, Xg1, Xc1, nullptr, nullptr, nullptr, 0);
  }
  his_add<<<4096, 256, 0, stream>>>(h0, h1, hisb, Xg0, Xc0, Xg1);
  // decoder
  for (int t = 0; t < 12; t++) {
    run_cell(2, 1, h0, Xg0, Xc0, Xg1, Xc1, nullptr, 0);
    run_cell(3, 64, h1, Xg1, Xc1, nullptr, nullptr, nullptr, 0);
    proj_k<<<64, 256, 0, stream>>>(h1, projW, projb, flg, d_out, Xg0, Xc0, t);
  }
}

// Round 9
// 3745.233 us; speedup vs baseline: 1.2627x; 1.2627x over previous
//
#include <hip/hip_runtime.h>
#include <stdint.h>
#include <string.h>
#include <math.h>

// DCRNN forward on MI355X. Runtime dtype detection (fp32 vs bf16) via enc0_bg==ones.
// P1..P4 precomputed bf16 (Pbig); gconv = GEMM1 (X@W -> VT scatter) + GEMM2 (P@V, K=2048,
// fused epilogue). gl16 direct-to-LDS staging, XOR-swizzled (slot=r*CH+(c^(r&7))).
// K-loop double-buffered, fine-grained s_waitcnt vmcnt(N) + raw s_barrier (AITER pattern).
// Grid discipline: every GEMM2 keeps >=256 blocks (1/CU) — round 8 showed 128-block
// grids cost ~1ms. Gate GEMM2 BM=64,BN=128 (ntiles=1): Pbig read exactly once, still
// 256 blocks. GEMM2 grids 1-D, bz=blk%32 -> same batch on same XCD (L2-resident B).
// Persistent X buffers maintained by epilogues (no pack kernels in the RNN loop).

using bfrag = __attribute__((__ext_vector_type__(8))) short;
using accv  = __attribute__((__ext_vector_type__(4))) float;

#define DEVI static __device__ __forceinline__

DEVI float bf2f(short x) {
  union { unsigned u; float f; } v; v.u = ((unsigned)(unsigned short)x) << 16; return v.f;
}
DEVI short f2bf(float f) {
  union { float f; unsigned u; } v; v.f = f;
  unsigned r = v.u + 0x7FFFu + ((v.u >> 16) & 1u);
  return (short)(r >> 16);
}
DEVI float ldx(const void* p, long i, int f32) {
  return f32 ? ((const float*)p)[i] : bf2f(((const short*)p)[i]);
}
DEVI void gl16(const short* g, short* l) {  // 16B direct global->LDS (dest = base + lane*16)
  __builtin_amdgcn_global_load_lds(
      (const __attribute__((address_space(1))) void*)g,
      (__attribute__((address_space(3))) void*)l, 16, 0, 0);
}

struct GP {
  const short* A;  long sA;  int lda;    // A: (M x K) row-major per batch (bf16 internal)
  const short* BT; long sBT; int ldbt;   // B transposed: (N x K) row-major per batch
  int K;
  short* C; long sC; int ldc;            // EPI 0/1 normal store
  short* CT;                             // EPI 2: plain transpose store; EPI 3: VT scatter
  const void* bias;                      // EXTERNAL bias (dtype per flag)
  const short* V0;                       // VT base (identity term) for EPI 4/5
  const int* flg;
  int outDim, oshift;
  int mtiles;                            // SWZ=1: M-tiles per batch
  const float* h; float* hw; const float* u;
  short* xc; int inpOff;                 // EPI4: Xc target (r*h), state col offset
  // EPI5 persistent-X maintenance:
  short* xgs; int xgsOff;                // Xg state cols target
  short* xch;                            // Xc base (hist cols partner, enc cell0)
  short* nxg; short* nxc;                // next-layer inp cols targets
  const void* hsrc; long hoff;           // hist source for next timestep (enc cell0)
};

// BM x BN tile, BK k-slab, THR threads, double-buffered LDS.
// SWZ=0: blockIdx.{x,y,z} = (mt, nt, bz). SWZ=1: 1-D grid, bz=blk%32, tile=blk/32,
//        mt=tile%mtiles, nt=tile/mtiles (XCD locality: same batch -> same blk%8).
// EPI: 0 plain; 1 bias+relu; 2 +transposed copy; 3 VT scatter (BM=128, THR=4*BN only);
//      4 gate epilogue; 5 cand epilogue.
template<int EPI, int BM, int BN, int BK, int THR, int SWZ>
__global__ __launch_bounds__(THR)
void gemm_k(GP p) {
  constexpr int W    = THR / 64;
  constexpr int WROW = BM / 32;
  constexpr int WCOL = (W / WROW < 1) ? 1 : W / WROW;
  constexpr int NT   = BN / (16 * WCOL);
  constexpr int CH   = BK / 8;                  // 16B chunks per row
  constexpr int AI   = (BM * CH) / THR;         // A chunks per thread per k-slab
  constexpr int BI   = (BN * CH) / THR;
  constexpr int LD   = AI + BI;                 // gl16 per wave per k-iter
  constexpr int TB   = (BM + BN) * BK;          // one buffer, shorts
  __shared__ __align__(16) short lds[2*TB];
  const int tid  = threadIdx.x;
  const int w    = tid >> 6;
  const int lane = tid & 63;
  const int quad = lane >> 4, l16 = lane & 15;
  const int rowW = (w % WROW) * 32;
  const int colW = (w / WROW) * (NT * 16);
  int m0, n0, bz;
  if constexpr (SWZ == 1) {
    const int blk = blockIdx.x;
    bz = blk & 31;
    const int tile = blk >> 5;
    m0 = (tile % p.mtiles) * BM;
    n0 = (tile / p.mtiles) * BN;
  } else {
    m0 = blockIdx.x * BM; n0 = blockIdx.y * BN; bz = blockIdx.z;
  }

  const short* Ab = p.A  + (long)bz * p.sA + m0 * (long)p.lda;
  const short* Bb = p.BT + (long)bz * p.sBT + n0 * (long)p.ldbt;

  accv acc[2][NT];
#pragma unroll
  for (int i = 0; i < 2; i++)
#pragma unroll
    for (int j = 0; j < NT; j++) { accv z = {0.f,0.f,0.f,0.f}; acc[i][j] = z; }

  // per-lane swizzled staging coords (slot s -> row r = s/CH, chunk c = (s%CH)^(r&7))
  const short* asrc[AI]; int aoff[AI];
#pragma unroll
  for (int i = 0; i < AI; i++) {
    const int s = (w*AI + i)*64 + lane;
    const int r = s / CH, c = (s % CH) ^ (r & 7);
    asrc[i] = Ab + (long)r * p.lda + c*8;
    aoff[i] = (w*AI + i)*512;
  }
  const short* bsrc[BI]; int boff[BI];
#pragma unroll
  for (int i = 0; i < BI; i++) {
    const int s = (w*BI + i)*64 + lane;
    const int r = s / CH, c = (s % CH) ^ (r & 7);
    bsrc[i] = Bb + (long)r * p.ldbt + c*8;
    boff[i] = BM*BK + (w*BI + i)*512;
  }

  const int nIter = p.K / BK;
  // prologue: issue slab 0 into buffer 0
#pragma unroll
  for (int i = 0; i < AI; i++) gl16(asrc[i], &lds[aoff[i]]);
#pragma unroll
  for (int i = 0; i < BI; i++) gl16(bsrc[i], &lds[boff[i]]);

  for (int it = 0; it < nIter; ++it) {
    const int bufO = (it & 1) * TB;
    if (it + 1 < nIter) {
      const int nxt = ((it + 1) & 1) * TB;
      const int kk = (it + 1) * BK;
#pragma unroll
      for (int i = 0; i < AI; i++) gl16(asrc[i] + kk, &lds[nxt + aoff[i]]);
#pragma unroll
      for (int i = 0; i < BI; i++) gl16(bsrc[i] + kk, &lds[nxt + boff[i]]);
      __builtin_amdgcn_s_waitcnt(0xF70 | LD);   // wait slab it; keep it+1 in flight
    } else {
      __builtin_amdgcn_s_waitcnt(0xF70);        // vmcnt(0)
    }
    asm volatile("s_barrier" ::: "memory");
#pragma unroll
    for (int ks = 0; ks < BK; ks += 32) {
      const int ch = (ks >> 3) + quad;          // 16B chunk index within row
      bfrag fa[2];
#pragma unroll
      for (int rt = 0; rt < 2; rt++) {
        const int ar = rowW + rt*16 + l16;
        fa[rt] = *(const bfrag*)&lds[bufO + (ar*CH + (ch ^ (ar & 7))) * 8];
      }
#pragma unroll
      for (int nt = 0; nt < NT; nt++) {
        const int br = colW + nt*16 + l16;
        bfrag fb = *(const bfrag*)&lds[bufO + BM*BK + (br*CH + (ch ^ (br & 7))) * 8];
        acc[0][nt] = __builtin_amdgcn_mfma_f32_16x16x32_bf16(fa[0], fb, acc[0][nt], 0, 0, 0);
        acc[1][nt] = __builtin_amdgcn_mfma_f32_16x16x32_bf16(fa[1], fb, acc[1][nt], 0, 0, 0);
      }
    }
    asm volatile("s_barrier" ::: "memory");
  }

  int f32 = 0;
  if constexpr (EPI == 1 || EPI == 4 || EPI == 5) f32 = *p.flg;

  if constexpr (EPI == 0 || EPI == 1 || EPI == 2) {
#pragma unroll
    for (int rt = 0; rt < 2; rt++) {
      const int rbase = m0 + rowW + rt*16 + quad*4;
#pragma unroll
      for (int nt = 0; nt < NT; nt++) {
        const int cc = n0 + colW + nt*16 + l16;
#pragma unroll
        for (int e = 0; e < 4; e++) {
          float val = acc[rt][nt][e];
          if constexpr (EPI == 1) { val += ldx(p.bias, cc, f32); val = val > 0.f ? val : 0.f; }
          p.C[(long)bz * p.sC + (long)(rbase + e) * p.ldc + cc] = f2bf(val);
        }
      }
    }
  }
  if constexpr (EPI == 2 || EPI == 3) {
    // regs -> LDS transposed tile (BN cols x BM rows, stride 136); BM=128, THR=4*BN
    __syncthreads();
#pragma unroll
    for (int rt = 0; rt < 2; rt++)
#pragma unroll
      for (int nt = 0; nt < NT; nt++)
#pragma unroll
        for (int e = 0; e < 4; e++)
          lds[(colW + nt*16 + l16)*136 + (rowW + rt*16 + quad*4 + e)] = f2bf(acc[rt][nt][e]);
    __syncthreads();
    const int c = tid >> 2, seg = tid & 3;     // c in [0,BN) when THR==4*BN
    const int cG = n0 + c;
    const short* sp = &lds[c*136 + seg*32];
    long dst;
    if constexpr (EPI == 3) {
      const int m  = cG >> p.oshift;
      const int o  = cG & (p.outDim - 1);
      const int bb = m0 >> 9;
      dst = ((long)((bb * p.outDim + o) * 5 + m) << 9) + (m0 & 511) + seg*32;
    } else {
      dst = (((long)bz << 9) + cG) * 512 + m0 + seg*32;
    }
    short* dp = p.CT + dst;
    *(bfrag*)(dp)      = *(const bfrag*)(sp);
    *(bfrag*)(dp + 8)  = *(const bfrag*)(sp + 8);
    *(bfrag*)(dp + 16) = *(const bfrag*)(sp + 16);
    *(bfrag*)(dp + 24) = *(const bfrag*)(sp + 24);
  }
  if constexpr (EPI == 4) {  // gate: sigmoid; o<64 -> Xc = r*h ; o>=64 -> u
#pragma unroll
    for (int rt = 0; rt < 2; rt++) {
      const int nb = m0 + rowW + rt*16 + quad*4;
#pragma unroll
      for (int nt = 0; nt < NT; nt++) {
        const int o = n0 + colW + nt*16 + l16;
        const float bv = ldx(p.bias, o, f32);
#pragma unroll
        for (int e = 0; e < 4; e++) {
          const int nn = nb + e;
          float val = acc[rt][nt][e] + bv +
                      bf2f(p.V0[(long)(bz * p.outDim + o) * 2560 + nn]);
          const float s = 1.f / (1.f + __expf(-val));
          const long bn = ((long)bz << 9) + nn;
          if (o < 64) p.xc[bn*128 + p.inpOff + o] = f2bf(s * p.h[(bn << 6) + o]);
          else        p.hw[(bn << 6) + (o - 64)] = s;
        }
      }
    }
  }
  if constexpr (EPI == 5) {  // cand: tanh; h = u*h + (1-u)*c; maintain persistent X bufs
#pragma unroll
    for (int rt = 0; rt < 2; rt++) {
      const int nb = m0 + rowW + rt*16 + quad*4;
#pragma unroll
      for (int nt = 0; nt < NT; nt++) {
        const int o = n0 + colW + nt*16 + l16;
        const float bv = ldx(p.bias, o, f32);
#pragma unroll
        for (int e = 0; e < 4; e++) {
          const int nn = nb + e;
          float val = acc[rt][nt][e] + bv +
                      bf2f(p.V0[(long)(bz * p.outDim + o) * 2560 + nn]);
          const float cth = tanhf(val);
          const long bn = ((long)bz << 9) + nn;
          const long idx = bn*64 + o;
          const float uo = p.u[idx];
          const float hn = uo * p.h[idx] + (1.f - uo) * cth;
          p.hw[idx] = hn;
          const short hb = f2bf(hn);
          if (p.xgs) p.xgs[bn*128 + p.xgsOff + o] = hb;
          if (p.nxg) { p.nxg[bn*128 + o] = hb; p.nxc[bn*128 + o] = hb; }
          if (p.hsrc != nullptr && o < 2) {
            const short hv = f2bf(ldx(p.hsrc, p.hoff + (long)bz*12288 + (long)nn*2 + o, f32));
            p.xgs[bn*128 + o] = hv;
            p.xch[bn*128 + o] = hv;
          }
        }
      }
    }
  }
}

// ---- small kernels ----

__global__ void detect_k(const short* bg0, int* flag) {
  if (threadIdx.x == 0 && blockIdx.x == 0)
    *flag = (bg0[0] == (short)0x3F80) ? 0 : 1;  // bf16 ones -> 0x3F80; fp32 ones low short = 0
}

__global__ void rowsum_inv(const void* adj, const int* flg, float* rsi) {
  const int f32 = *flg;
  const int wid  = (blockIdx.x * 256 + threadIdx.x) >> 6;  // row index b*512+i
  const int lane = threadIdx.x & 63;
  const long base = (long)wid * 512;
  float s = 0.f;
  for (int j = lane; j < 512; j += 64) s += ldx(adj, base + j, f32);
  for (int off = 32; off > 0; off >>= 1) s += __shfl_down(s, off, 64);
  if (lane == 0) rsi[wid] = 1.f / (1.f + s);
}

__global__ void colsum_inv(const void* adj, const int* flg, float* csi) {
  const int f32 = *flg;
  const int i = blockIdx.x * 256 + threadIdx.x;  // b*512+col
  const int b = i >> 9, col = i & 511;
  const long base = (long)b * 262144 + col;
  float s = 1.f;
  for (int j = 0; j < 512; j++) s += ldx(adj, base + (long)j * 512, f32);
  csi[i] = 1.f / s;
}

// A1 -> Pbig block0 (ld 2048); A1T, A2 (512x512, ld 512) per batch
__global__ __launch_bounds__(256)
void build_a(const void* adj, const int* flg, const float* rsi, const float* csi,
             short* Pbig, short* A1T, short* A2) {
  const int f32 = *flg;
  __shared__ __align__(16) float t[64 * 65];
  const int b = blockIdx.z, ti = blockIdx.x, tj = blockIdx.y;
  const int tid = threadIdx.x;
  const int r = tid >> 2, cs = (tid & 3) * 16;
  const long base = (long)b * 262144 + (long)(ti*64 + r) * 512 + tj*64 + cs;
#pragma unroll
  for (int j = 0; j < 16; j++) t[r*65 + cs + j] = ldx(adj, base + j, f32);
  __syncthreads();
  {
    const int gi = ti*64 + r;
    const float inv = rsi[b*512 + gi];
    short o[16];
#pragma unroll
    for (int j = 0; j < 16; j++) {
      const int gj = tj*64 + cs + j;
      o[j] = f2bf((t[r*65 + cs + j] + (gi == gj ? 1.f : 0.f)) * inv);
    }
    short* dp = Pbig + ((long)(b*512 + gi) << 11) + tj*64 + cs;
    bfrag v0 = {o[0],o[1],o[2],o[3],o[4],o[5],o[6],o[7]};
    bfrag v1 = {o[8],o[9],o[10],o[11],o[12],o[13],o[14],o[15]};
    *(bfrag*)dp = v0; *(bfrag*)(dp + 8) = v1;
  }
  {
    const int y = tj*64 + r;  // output row for A1T and A2
    const float invc = csi[b*512 + y];
    short o1[16], o2[16];
#pragma unroll
    for (int j = 0; j < 16; j++) {
      const int x = ti*64 + cs + j;
      const float av = t[(cs + j)*65 + r];     // adj[x][y]
      const float d = (x == y) ? 1.f : 0.f;
      o1[j] = f2bf((av + d) * rsi[b*512 + x]);  // A1T[y][x] = A1[x][y]
      o2[j] = f2bf((av + d) * invc);            // A2[y][x]  = (adj[x][y]+d)/cs[y]
    }
    short* d1 = A1T + ((long)(b*512 + y) << 9) + ti*64 + cs;
    short* d2 = A2  + ((long)(b*512 + y) << 9) + ti*64 + cs;
    bfrag a0 = {o1[0],o1[1],o1[2],o1[3],o1[4],o1[5],o1[6],o1[7]};
    bfrag a1 = {o1[8],o1[9],o1[10],o1[11],o1[12],o1[13],o1[14],o1[15]};
    bfrag b0 = {o2[0],o2[1],o2[2],o2[3],o2[4],o2[5],o2[6],o2[7]};
    bfrag b1 = {o2[8],o2[9],o2[10],o2[11],o2[12],o2[13],o2[14],o2[15]};
    *(bfrag*)d1 = a0; *(bfrag*)(d1 + 8) = a1;
    *(bfrag*)d2 = b0; *(bfrag*)(d2 + 8) = b1;
  }
}

// folded + transposed gconv weights: WT[(m*out+o)*128 + feat]; W row index = feat*5 + m
__global__ void build_wcat(const void* W, const int* flg, short* WT, int f, int out) {
  const int f32 = *flg;
  const int i = blockIdx.x * 256 + threadIdx.x;
  if (i >= 5 * out * 128) return;
  const int feat = i & 127;
  const int mo = i >> 7;
  const int m = mo / out;
  const int o = mo - m * out;
  float v = 0.f;
  if (feat < f) {
    const long base = (long)feat * 5 * out;
    const float w0 = ldx(W, base + 0*out + o, f32);
    const float w1 = ldx(W, base + 1*out + o, f32);
    const float w2 = ldx(W, base + 2*out + o, f32);
    const float w3 = ldx(W, base + 3*out + o, f32);
    const float w4 = ldx(W, base + 4*out + o, f32);
    v = (m == 0) ? (w0 - w2) : (m == 1) ? (w1 - w4) : (m == 2) ? 2.f*w2
      : (m == 3) ? w3 : 2.f*w4;
  }
  WT[(long)mo * 128 + feat] = f2bf(v);
}

__global__ void build_fc1T(const void* W, const int* flg, short* WT) {
  const int f32 = *flg;
  const int i = blockIdx.x * 256 + threadIdx.x;  // 256*128
  const int o = i >> 7, k = i & 127;
  WT[i] = (k < 96) ? f2bf(ldx(W, (long)k*256 + o, f32)) : (short)0;
}
__global__ void build_fc2T(const void* W, const int* flg, short* WT) {
  const int f32 = *flg;
  const int i = blockIdx.x * 256 + threadIdx.x;  // 64*256
  const int o = i >> 8, k = i & 255;
  WT[i] = f2bf(ldx(W, (long)k*64 + o, f32));
}
__global__ void pack_hid(const void* hd, const int* flg, short* hp) {
  const int f32 = *flg;
  const int i = blockIdx.x * 256 + threadIdx.x;  // 16384*128
  const int row = i >> 7, k = i & 127;
  hp[i] = (k < 96) ? f2bf(ldx(hd, (long)row*96 + k, f32)) : (short)0;
}

// seed encoder t=0 hist cols into Xg0/Xc0
__global__ void seed_hist(const void* hist, const int* flg, short* Xg0, short* Xc0) {
  const int f32 = *flg;
  const int i = blockIdx.x * 256 + threadIdx.x;  // 32768
  const int row = i >> 1, c = i & 1;
  const short v = f2bf(ldx(hist, (long)(row >> 9)*12288 + (long)(row & 511)*2 + c, f32));
  Xg0[(long)row*128 + c] = v;
  Xc0[(long)row*128 + c] = v;
}

// enc->dec boundary: h += his; rewrite Xg0 (dec layout: col0=0, state cols 1..64) and
// Xg1 state cols 64..127; zero Xc0 col0.
__global__ void his_add(float* h0, float* h1, const short* his,
                        short* Xg0, short* Xc0, short* Xg1) {
  const int i = blockIdx.x * 256 + threadIdx.x;  // 1048576
  const int row = i >> 6, o = i & 63;
  const float v = bf2f(his[i]);
  const float a = h0[i] + v, b = h1[i] + v;
  h0[i] = a; h1[i] = b;
  Xg0[(long)row*128 + 1 + o]  = f2bf(a);
  Xg1[(long)row*128 + 64 + o] = f2bf(b);
  if (o == 0) { Xg0[(long)row*128] = 0; Xc0[(long)row*128] = 0; }
}

__global__ void proj_k(const float* h1, const void* pw, const void* pb, const int* flg,
                       void* dout, short* Xg0, short* Xc0, int t) {
  const int f32 = *flg;
  const int i = blockIdx.x * 256 + threadIdx.x;  // 16384
  const float* hr = h1 + (long)i * 64;
  float s = ldx(pb, 0, f32);
  for (int j = 0; j < 64; j++) s += hr[j] * ldx(pw, j, f32);
  if (f32) ((float*)dout)[i*12 + t] = s;
  else     ((short*)dout)[i*12 + t] = f2bf(s);
  const short v = f2bf(s);
  Xg0[(long)i*128] = v;
  Xc0[(long)i*128] = v;
}

extern "C" void kernel_launch(void* const* d_in, const int* in_sizes, int n_in,
                              void* d_out, int out_size, void* d_ws, size_t ws_size,
                              hipStream_t stream) {
  (void)in_sizes; (void)n_in; (void)out_size;
  const void* hist   = d_in[0];
  const void* hidden = d_in[1];
  const void* adj    = d_in[2];
  const void* Wg[4] = {d_in[3], d_in[7],  d_in[11], d_in[15]};
  const void* bg[4] = {d_in[4], d_in[8],  d_in[12], d_in[16]};
  const void* Wc[4] = {d_in[5], d_in[9],  d_in[13], d_in[17]};
  const void* bc[4] = {d_in[6], d_in[10], d_in[14], d_in[18]};
  const void* projW = d_in[19];
  const void* projb = d_in[20];
  const void* fc1W  = d_in[21];
  const void* fc1b  = d_in[22];
  const void* fc2W  = d_in[23];
  const void* fc2b  = d_in[24];

  // ---- workspace layout: persistent + phase-union (lifetimes disjoint) ----
  char* wp = (char*)d_ws;
  auto alloc = [&](size_t bytes) { char* r = wp; wp += (bytes + 255) & ~(size_t)255; return r; };
  short* Pbig = (short*)alloc(32ull*512*2048*2);   // [A1 | A1^2 | A2A1 | A2^2A1], ld 2048
  float* ub   = (float*)alloc(16384ull*64*4);
  float* h0   = (float*)alloc(16384ull*64*4);
  float* h1   = (float*)alloc(16384ull*64*4);
  short* hisb = (short*)alloc(16384ull*64*2);
  short* wctg[4]; for (int i = 0; i < 4; i++) wctg[i] = (short*)alloc(640*128*2);
  short* wctc[4]; for (int i = 0; i < 4; i++) wctc[i] = (short*)alloc(320*128*2);
  float* rsi = (float*)alloc(16384*4);
  float* csi = (float*)alloc(16384*4);
  int*   flg = (int*)alloc(256);
  // phase-union region (phase lifetimes disjoint)
  char* ubase = wp;
  short* hidp = (short*)ubase;                         // phase0: 4,194,304 B
  short* mid  = (short*)(ubase + 4194304);             //          8,388,608 B
  short* fc1T = (short*)(ubase + 4194304 + 8388608);   //          65,536 B
  short* fc2T = (short*)(ubase + 4194304 + 8388608 + 65536);
  short* A1T  = (short*)ubase;                         // phase1: 16,777,216 B each
  short* A2   = (short*)(ubase + 16777216);
  short* P3T  = (short*)(ubase + 33554432);
  short* VTg  = (short*)ubase;                         // phase2: 20,971,520 B
  short* VTc  = (short*)(ubase + 20971520);            //         10,485,760 B
  short* Xg0  = (short*)(ubase + 31457280);            //          4,194,304 B each
  short* Xc0  = (short*)(ubase + 35651584);
  short* Xg1  = (short*)(ubase + 39845888);
  short* Xc1  = (short*)(ubase + 44040192);
  const size_t need = (size_t)(ubase - (char*)d_ws) + 48234496 + 2097152;
  if (ws_size < need) return;  // d_out stays zero: finite-absmax diagnostic signature

  detect_k<<<1, 64, 0, stream>>>((const short*)bg[0], flg);
  hipMemsetAsync(h0, 0, 16384ull*64*4, stream);
  hipMemsetAsync(h1, 0, 16384ull*64*4, stream);

  // ---- phase 0: weight prep + fc_his ----
  const int fdim[4] = {66, 128, 65, 128};  // enc0, enc1, dec0, dec1
  for (int i = 0; i < 4; i++) {
    build_wcat<<<320, 256, 0, stream>>>(Wg[i], flg, wctg[i], fdim[i], 128);
    build_wcat<<<160, 256, 0, stream>>>(Wc[i], flg, wctc[i], fdim[i], 64);
  }
  build_fc1T<<<128, 256, 0, stream>>>(fc1W, flg, fc1T);
  build_fc2T<<<64, 256, 0, stream>>>(fc2W, flg, fc2T);
  pack_hid<<<8192, 256, 0, stream>>>(hidden, flg, hidp);

  GP p;
  // fc_his: his = relu(relu(hid @ fc1 + b1) @ fc2 + b2)
  p = GP{}; p.A = hidp; p.lda = 128; p.BT = fc1T; p.ldbt = 128; p.K = 128;
  p.C = mid; p.ldc = 256; p.bias = fc1b; p.flg = flg;
  gemm_k<1,128,64,64,256,0><<<dim3(128, 4, 1), 256, 0, stream>>>(p);
  p = GP{}; p.A = mid; p.lda = 256; p.BT = fc2T; p.ldbt = 256; p.K = 256;
  p.C = hisb; p.ldc = 64; p.bias = fc2b; p.flg = flg;
  gemm_k<1,128,64,64,256,0><<<dim3(128, 1, 1), 256, 0, stream>>>(p);

  // ---- phase 1: diffusion matrices ----
  rowsum_inv<<<4096, 256, 0, stream>>>(adj, flg, rsi);
  colsum_inv<<<64, 256, 0, stream>>>(adj, flg, csi);
  build_a<<<dim3(8, 8, 32), 256, 0, stream>>>(adj, flg, rsi, csi, Pbig, A1T, A2);

  p = GP{}; p.A = Pbig; p.sA = 512*2048; p.lda = 2048;    // P2 = A1 @ A1
  p.BT = A1T; p.sBT = 512*512; p.ldbt = 512; p.K = 512;
  p.C = Pbig + 512; p.sC = 512*2048; p.ldc = 2048; p.flg = flg;
  gemm_k<0,128,64,64,256,0><<<dim3(4, 8, 32), 256, 0, stream>>>(p);
  p = GP{}; p.A = A2; p.sA = 512*512; p.lda = 512;        // P3 = A2 @ A1 (+ P3T)
  p.BT = A1T; p.sBT = 512*512; p.ldbt = 512; p.K = 512;
  p.C = Pbig + 1024; p.sC = 512*2048; p.ldc = 2048; p.CT = P3T; p.flg = flg;
  gemm_k<2,128,64,64,256,0><<<dim3(4, 8, 32), 256, 0, stream>>>(p);
  p = GP{}; p.A = A2; p.sA = 512*512; p.lda = 512;        // P4 = A2 @ P3
  p.BT = P3T; p.sBT = 512*512; p.ldbt = 512; p.K = 512;
  p.C = Pbig + 1536; p.sC = 512*2048; p.ldc = 2048; p.flg = flg;
  gemm_k<0,128,64,64,256,0><<<dim3(4, 8, 32), 256, 0, stream>>>(p);

  // ---- phase 2: RNN (persistent X buffers) ----
  hipMemsetAsync(Xg0, 0, 4ull*4194304, stream);  // Xg0,Xc0,Xg1,Xc1 contiguous
  seed_hist<<<128, 256, 0, stream>>>(hist, flg, Xg0, Xc0);

  // cell: wi weight idx, inpOff state col, hstate; EPI5 maintenance params
  auto run_cell = [&](int wi, int inpOff, float* hstate, short* XgL, short* XcL,
                      short* nxg, short* nxc, const void* hsrc, long hoff) {
    GP q;
    // GEMM1 gate: XgL(16384x128) @ WcatT -> VTg scatter (BN=128: A read 5x, 640 blocks)
    q = GP{}; q.A = XgL; q.lda = 128; q.BT = wctg[wi]; q.ldbt = 128; q.K = 128;
    q.CT = VTg; q.outDim = 128; q.oshift = 7; q.flg = flg;
    gemm_k<3,128,128,64,512,0><<<dim3(128, 5, 1), 512, 0, stream>>>(q);
    // GEMM2 gate: Pbig @ U (K=2048) -> sigmoid -> (r*h into XcL, u)
    // BM=64,BN=128: ntiles=1 -> Pbig read exactly once; 256 blocks, XCD swizzle
    q = GP{}; q.A = Pbig; q.sA = 512*2048; q.lda = 2048;
    q.BT = VTg + 512; q.sBT = 128*2560; q.ldbt = 2560; q.K = 2048;
    q.V0 = VTg; q.outDim = 128; q.bias = bg[wi]; q.flg = flg; q.mtiles = 8;
    q.h = hstate; q.hw = ub; q.xc = XcL; q.inpOff = inpOff;
    gemm_k<4,64,128,64,512,1><<<dim3(256, 1, 1), 512, 0, stream>>>(q);
    // GEMM1 cand
    q = GP{}; q.A = XcL; q.lda = 128; q.BT = wctc[wi]; q.ldbt = 128; q.K = 128;
    q.CT = VTc; q.outDim = 64; q.oshift = 6; q.flg = flg;
    gemm_k<3,128,64,64,256,0><<<dim3(128, 5, 1), 256, 0, stream>>>(q);
    // GEMM2 cand: tanh + h update + persistent-X maintenance
    // BM=64,BN=64: ntiles=1 -> Pbig read once; 256 blocks, XCD swizzle
    q = GP{}; q.A = Pbig; q.sA = 512*2048; q.lda = 2048;
    q.BT = VTc + 512; q.sBT = 64*2560; q.ldbt = 2560; q.K = 2048;
    q.V0 = VTc; q.outDim = 64; q.bias = bc[wi]; q.flg = flg; q.mtiles = 8;
    q.h = hstate; q.hw = hstate; q.u = ub;
    q.xgs = XgL; q.xgsOff = inpOff; q.xch = XcL;
    q.nxg = nxg; q.nxc = nxc; q.hsrc = hsrc; q.hoff = hoff;
    gemm_k<5,64,64,64,256,1><<<dim3(256, 1, 1), 256, 0, stream>>>(q);
  };

  // encoder
  for (int t = 0; t < 12; t++) {
    run_cell(0, 2, h0, Xg0, Xc0, Xg1, Xc1,
             (t < 11) ? hist : nullptr, (long)(t + 1) * 1024);
    run_cell(1, 64, h1, Xg1, Xc1, nullptr, nullptr, nullptr, 0);
  }
  his_add<<<4096, 256, 0, stream>>>(h0, h1, hisb, Xg0, Xc0, Xg1);
  // decoder
  for (int t = 0; t < 12; t++) {
    run_cell(2, 1, h0, Xg0, Xc0, Xg1, Xc1, nullptr, 0);
    run_cell(3, 64, h1, Xg1, Xc1, nullptr, nullptr, nullptr, 0);
    proj_k<<<64, 256, 0, stream>>>(h1, projW, projb, flg, d_out, Xg0, Xc0, t);
  }
}

// Round 10
// 3582.706 us; speedup vs baseline: 1.3200x; 1.0454x over previous
//
#include <hip/hip_runtime.h>
#include <stdint.h>
#include <string.h>
#include <math.h>

// DCRNN forward on MI355X. Runtime dtype detection (fp32 vs bf16) via enc0_bg==ones.
// P1..P4 precomputed bf16 (Pbig); gconv = GEMM1 (X@W -> VT scatter) + GEMM2 (P@V, K=2048,
// fused epilogue). gl16 direct-to-LDS staging, XOR-swizzled (slot=r*CH+(c^(r&7))).
// K-loop PIPE-stage pipelined with fine-grained s_waitcnt vmcnt((PIPE-1)*LD) + raw
// s_barrier: slab it's loads get PIPE-1 iterations of flight time (GEMM2s are
// load-latency-bound at 1 block/CU: 24KB/iter, ~78cyc compute vs ~500+cyc LLC latency).
// GEMM2s: PIPE=4 (96/64 KB LDS). GEMM1s/P-build: PIPE=2 (K small / multi-block).
// GEMM2 grids 1-D, bz=blk%32 -> same batch on same XCD (L2-resident B re-reads).
// Grid discipline: every GEMM2 keeps >=256 blocks (round 8: 128-block grids cost ~1ms).
// Persistent X buffers maintained by epilogues (no pack kernels in the RNN loop).

using bfrag = __attribute__((__ext_vector_type__(8))) short;
using accv  = __attribute__((__ext_vector_type__(4))) float;

#define DEVI static __device__ __forceinline__

DEVI float bf2f(short x) {
  union { unsigned u; float f; } v; v.u = ((unsigned)(unsigned short)x) << 16; return v.f;
}
DEVI short f2bf(float f) {
  union { float f; unsigned u; } v; v.f = f;
  unsigned r = v.u + 0x7FFFu + ((v.u >> 16) & 1u);
  return (short)(r >> 16);
}
DEVI float ldx(const void* p, long i, int f32) {
  return f32 ? ((const float*)p)[i] : bf2f(((const short*)p)[i]);
}
DEVI void gl16(const short* g, short* l) {  // 16B direct global->LDS (dest = base + lane*16)
  __builtin_amdgcn_global_load_lds(
      (const __attribute__((address_space(1))) void*)g,
      (__attribute__((address_space(3))) void*)l, 16, 0, 0);
}

struct GP {
  const short* A;  long sA;  int lda;    // A: (M x K) row-major per batch (bf16 internal)
  const short* BT; long sBT; int ldbt;   // B transposed: (N x K) row-major per batch
  int K;
  short* C; long sC; int ldc;            // EPI 0/1 normal store
  short* CT;                             // EPI 2: plain transpose store; EPI 3: VT scatter
  const void* bias;                      // EXTERNAL bias (dtype per flag)
  const short* V0;                       // VT base (identity term) for EPI 4/5
  const int* flg;
  int outDim, oshift;
  int mtiles;                            // SWZ=1: M-tiles per batch
  const float* h; float* hw; const float* u;
  short* xc; int inpOff;                 // EPI4: Xc target (r*h), state col offset
  // EPI5 persistent-X maintenance:
  short* xgs; int xgsOff;                // Xg state cols target
  short* xch;                            // Xc base (hist cols partner, enc cell0)
  short* nxg; short* nxc;                // next-layer inp cols targets
  const void* hsrc; long hoff;           // hist source for next timestep (enc cell0)
};

// BM x BN tile, BK k-slab, THR threads, PIPE-stage LDS pipeline.
// SWZ=0: blockIdx.{x,y,z} = (mt, nt, bz). SWZ=1: 1-D grid, bz=blk%32, tile=blk/32,
//        mt=tile%mtiles, nt=tile/mtiles (XCD locality: same batch -> same blk%8).
// EPI: 0 plain; 1 bias+relu; 2 +transposed copy; 3 VT scatter (BM=128, THR=4*BN only);
//      4 gate epilogue; 5 cand epilogue.
template<int EPI, int BM, int BN, int BK, int THR, int SWZ, int PIPE>
__global__ __launch_bounds__(THR)
void gemm_k(GP p) {
  constexpr int W    = THR / 64;
  constexpr int WROW = BM / 32;
  constexpr int WCOL = (W / WROW < 1) ? 1 : W / WROW;
  constexpr int NT   = BN / (16 * WCOL);
  constexpr int CH   = BK / 8;                  // 16B chunks per row
  constexpr int AI   = (BM * CH) / THR;         // A chunks per thread per k-slab
  constexpr int BI   = (BN * CH) / THR;
  constexpr int LD   = AI + BI;                 // gl16 per wave per k-iter
  constexpr int TB   = (BM + BN) * BK;          // one buffer, shorts
  __shared__ __align__(16) short lds[PIPE*TB];
  const int tid  = threadIdx.x;
  const int w    = tid >> 6;
  const int lane = tid & 63;
  const int quad = lane >> 4, l16 = lane & 15;
  const int rowW = (w % WROW) * 32;
  const int colW = (w / WROW) * (NT * 16);
  int m0, n0, bz;
  if constexpr (SWZ == 1) {
    const int blk = blockIdx.x;
    bz = blk & 31;
    const int tile = blk >> 5;
    m0 = (tile % p.mtiles) * BM;
    n0 = (tile / p.mtiles) * BN;
  } else {
    m0 = blockIdx.x * BM; n0 = blockIdx.y * BN; bz = blockIdx.z;
  }

  const short* Ab = p.A  + (long)bz * p.sA + m0 * (long)p.lda;
  const short* Bb = p.BT + (long)bz * p.sBT + n0 * (long)p.ldbt;

  accv acc[2][NT];
#pragma unroll
  for (int i = 0; i < 2; i++)
#pragma unroll
    for (int j = 0; j < NT; j++) { accv z = {0.f,0.f,0.f,0.f}; acc[i][j] = z; }

  // per-lane swizzled staging coords (slot s -> row r = s/CH, chunk c = (s%CH)^(r&7))
  const short* asrc[AI]; int aoff[AI];
#pragma unroll
  for (int i = 0; i < AI; i++) {
    const int s = (w*AI + i)*64 + lane;
    const int r = s / CH, c = (s % CH) ^ (r & 7);
    asrc[i] = Ab + (long)r * p.lda + c*8;
    aoff[i] = (w*AI + i)*512;
  }
  const short* bsrc[BI]; int boff[BI];
#pragma unroll
  for (int i = 0; i < BI; i++) {
    const int s = (w*BI + i)*64 + lane;
    const int r = s / CH, c = (s % CH) ^ (r & 7);
    bsrc[i] = Bb + (long)r * p.ldbt + c*8;
    boff[i] = BM*BK + (w*BI + i)*512;
  }

  const int nIter = p.K / BK;
  // prologue: issue slabs 0..PIPE-2
#pragma unroll
  for (int s = 0; s < PIPE-1; ++s) {
    if (s < nIter) {
      const int kk = s * BK;
#pragma unroll
      for (int i = 0; i < AI; i++) gl16(asrc[i] + kk, &lds[s*TB + aoff[i]]);
#pragma unroll
      for (int i = 0; i < BI; i++) gl16(bsrc[i] + kk, &lds[s*TB + boff[i]]);
    }
  }

  for (int it = 0; it < nIter; ++it) {
    const int bufO = (it & (PIPE-1)) * TB;
    if (it + PIPE - 1 < nIter) {
      const int nxt = ((it + PIPE - 1) & (PIPE-1)) * TB;
      const int kk = (it + PIPE - 1) * BK;
#pragma unroll
      for (int i = 0; i < AI; i++) gl16(asrc[i] + kk, &lds[nxt + aoff[i]]);
#pragma unroll
      for (int i = 0; i < BI; i++) gl16(bsrc[i] + kk, &lds[nxt + boff[i]]);
    }
    // wait until slab `it` landed: newest (#slabs in flight)*LD may stay outstanding
    const int rem = nIter - 1 - it;
    if (rem >= PIPE-1)   __builtin_amdgcn_s_waitcnt(0xF70 | ((PIPE-1)*LD));
    else if (rem == 2)   __builtin_amdgcn_s_waitcnt(0xF70 | (2*LD));
    else if (rem == 1)   __builtin_amdgcn_s_waitcnt(0xF70 | (1*LD));
    else                 __builtin_amdgcn_s_waitcnt(0xF70);
    asm volatile("s_barrier" ::: "memory");
#pragma unroll
    for (int ks = 0; ks < BK; ks += 32) {
      const int ch = (ks >> 3) + quad;          // 16B chunk index within row
      bfrag fa[2];
#pragma unroll
      for (int rt = 0; rt < 2; rt++) {
        const int ar = rowW + rt*16 + l16;
        fa[rt] = *(const bfrag*)&lds[bufO + (ar*CH + (ch ^ (ar & 7))) * 8];
      }
#pragma unroll
      for (int nt = 0; nt < NT; nt++) {
        const int br = colW + nt*16 + l16;
        bfrag fb = *(const bfrag*)&lds[bufO + BM*BK + (br*CH + (ch ^ (br & 7))) * 8];
        acc[0][nt] = __builtin_amdgcn_mfma_f32_16x16x32_bf16(fa[0], fb, acc[0][nt], 0, 0, 0);
        acc[1][nt] = __builtin_amdgcn_mfma_f32_16x16x32_bf16(fa[1], fb, acc[1][nt], 0, 0, 0);
      }
    }
    asm volatile("s_barrier" ::: "memory");
  }

  int f32 = 0;
  if constexpr (EPI == 1 || EPI == 4 || EPI == 5) f32 = *p.flg;

  if constexpr (EPI == 0 || EPI == 1 || EPI == 2) {
#pragma unroll
    for (int rt = 0; rt < 2; rt++) {
      const int rbase = m0 + rowW + rt*16 + quad*4;
#pragma unroll
      for (int nt = 0; nt < NT; nt++) {
        const int cc = n0 + colW + nt*16 + l16;
#pragma unroll
        for (int e = 0; e < 4; e++) {
          float val = acc[rt][nt][e];
          if constexpr (EPI == 1) { val += ldx(p.bias, cc, f32); val = val > 0.f ? val : 0.f; }
          p.C[(long)bz * p.sC + (long)(rbase + e) * p.ldc + cc] = f2bf(val);
        }
      }
    }
  }
  if constexpr (EPI == 2 || EPI == 3) {
    // regs -> LDS transposed tile (BN cols x BM rows, stride 136); BM=128, THR=4*BN
    __syncthreads();
#pragma unroll
    for (int rt = 0; rt < 2; rt++)
#pragma unroll
      for (int nt = 0; nt < NT; nt++)
#pragma unroll
        for (int e = 0; e < 4; e++)
          lds[(colW + nt*16 + l16)*136 + (rowW + rt*16 + quad*4 + e)] = f2bf(acc[rt][nt][e]);
    __syncthreads();
    const int c = tid >> 2, seg = tid & 3;     // c in [0,BN) when THR==4*BN
    const int cG = n0 + c;
    const short* sp = &lds[c*136 + seg*32];
    long dst;
    if constexpr (EPI == 3) {
      const int m  = cG >> p.oshift;
      const int o  = cG & (p.outDim - 1);
      const int bb = m0 >> 9;
      dst = ((long)((bb * p.outDim + o) * 5 + m) << 9) + (m0 & 511) + seg*32;
    } else {
      dst = (((long)bz << 9) + cG) * 512 + m0 + seg*32;
    }
    short* dp = p.CT + dst;
    *(bfrag*)(dp)      = *(const bfrag*)(sp);
    *(bfrag*)(dp + 8)  = *(const bfrag*)(sp + 8);
    *(bfrag*)(dp + 16) = *(const bfrag*)(sp + 16);
    *(bfrag*)(dp + 24) = *(const bfrag*)(sp + 24);
  }
  if constexpr (EPI == 4) {  // gate: sigmoid; o<64 -> Xc = r*h ; o>=64 -> u
#pragma unroll
    for (int rt = 0; rt < 2; rt++) {
      const int nb = m0 + rowW + rt*16 + quad*4;
#pragma unroll
      for (int nt = 0; nt < NT; nt++) {
        const int o = n0 + colW + nt*16 + l16;
        const float bv = ldx(p.bias, o, f32);
#pragma unroll
        for (int e = 0; e < 4; e++) {
          const int nn = nb + e;
          float val = acc[rt][nt][e] + bv +
                      bf2f(p.V0[(long)(bz * p.outDim + o) * 2560 + nn]);
          const float s = 1.f / (1.f + __expf(-val));
          const long bn = ((long)bz << 9) + nn;
          if (o < 64) p.xc[bn*128 + p.inpOff + o] = f2bf(s * p.h[(bn << 6) + o]);
          else        p.hw[(bn << 6) + (o - 64)] = s;
        }
      }
    }
  }
  if constexpr (EPI == 5) {  // cand: tanh; h = u*h + (1-u)*c; maintain persistent X bufs
#pragma unroll
    for (int rt = 0; rt < 2; rt++) {
      const int nb = m0 + rowW + rt*16 + quad*4;
#pragma unroll
      for (int nt = 0; nt < NT; nt++) {
        const int o = n0 + colW + nt*16 + l16;
        const float bv = ldx(p.bias, o, f32);
#pragma unroll
        for (int e = 0; e < 4; e++) {
          const int nn = nb + e;
          float val = acc[rt][nt][e] + bv +
                      bf2f(p.V0[(long)(bz * p.outDim + o) * 2560 + nn]);
          const float cth = tanhf(val);
          const long bn = ((long)bz << 9) + nn;
          const long idx = bn*64 + o;
          const float uo = p.u[idx];
          const float hn = uo * p.h[idx] + (1.f - uo) * cth;
          p.hw[idx] = hn;
          const short hb = f2bf(hn);
          if (p.xgs) p.xgs[bn*128 + p.xgsOff + o] = hb;
          if (p.nxg) { p.nxg[bn*128 + o] = hb; p.nxc[bn*128 + o] = hb; }
          if (p.hsrc != nullptr && o < 2) {
            const short hv = f2bf(ldx(p.hsrc, p.hoff + (long)bz*12288 + (long)nn*2 + o, f32));
            p.xgs[bn*128 + o] = hv;
            p.xch[bn*128 + o] = hv;
          }
        }
      }
    }
  }
}

// ---- small kernels ----

__global__ void detect_k(const short* bg0, int* flag) {
  if (threadIdx.x == 0 && blockIdx.x == 0)
    *flag = (bg0[0] == (short)0x3F80) ? 0 : 1;  // bf16 ones -> 0x3F80; fp32 ones low short = 0
}

__global__ void rowsum_inv(const void* adj, const int* flg, float* rsi) {
  const int f32 = *flg;
  const int wid  = (blockIdx.x * 256 + threadIdx.x) >> 6;  // row index b*512+i
  const int lane = threadIdx.x & 63;
  const long base = (long)wid * 512;
  float s = 0.f;
  for (int j = lane; j < 512; j += 64) s += ldx(adj, base + j, f32);
  for (int off = 32; off > 0; off >>= 1) s += __shfl_down(s, off, 64);
  if (lane == 0) rsi[wid] = 1.f / (1.f + s);
}

__global__ void colsum_inv(const void* adj, const int* flg, float* csi) {
  const int f32 = *flg;
  const int i = blockIdx.x * 256 + threadIdx.x;  // b*512+col
  const int b = i >> 9, col = i & 511;
  const long base = (long)b * 262144 + col;
  float s = 1.f;
  for (int j = 0; j < 512; j++) s += ldx(adj, base + (long)j * 512, f32);
  csi[i] = 1.f / s;
}

// A1 -> Pbig block0 (ld 2048); A1T, A2 (512x512, ld 512) per batch
__global__ __launch_bounds__(256)
void build_a(const void* adj, const int* flg, const float* rsi, const float* csi,
             short* Pbig, short* A1T, short* A2) {
  const int f32 = *flg;
  __shared__ __align__(16) float t[64 * 65];
  const int b = blockIdx.z, ti = blockIdx.x, tj = blockIdx.y;
  const int tid = threadIdx.x;
  const int r = tid >> 2, cs = (tid & 3) * 16;
  const long base = (long)b * 262144 + (long)(ti*64 + r) * 512 + tj*64 + cs;
#pragma unroll
  for (int j = 0; j < 16; j++) t[r*65 + cs + j] = ldx(adj, base + j, f32);
  __syncthreads();
  {
    const int gi = ti*64 + r;
    const float inv = rsi[b*512 + gi];
    short o[16];
#pragma unroll
    for (int j = 0; j < 16; j++) {
      const int gj = tj*64 + cs + j;
      o[j] = f2bf((t[r*65 + cs + j] + (gi == gj ? 1.f : 0.f)) * inv);
    }
    short* dp = Pbig + ((long)(b*512 + gi) << 11) + tj*64 + cs;
    bfrag v0 = {o[0],o[1],o[2],o[3],o[4],o[5],o[6],o[7]};
    bfrag v1 = {o[8],o[9],o[10],o[11],o[12],o[13],o[14],o[15]};
    *(bfrag*)dp = v0; *(bfrag*)(dp + 8) = v1;
  }
  {
    const int y = tj*64 + r;  // output row for A1T and A2
    const float invc = csi[b*512 + y];
    short o1[16], o2[16];
#pragma unroll
    for (int j = 0; j < 16; j++) {
      const int x = ti*64 + cs + j;
      const float av = t[(cs + j)*65 + r];     // adj[x][y]
      const float d = (x == y) ? 1.f : 0.f;
      o1[j] = f2bf((av + d) * rsi[b*512 + x]);  // A1T[y][x] = A1[x][y]
      o2[j] = f2bf((av + d) * invc);            // A2[y][x]  = (adj[x][y]+d)/cs[y]
    }
    short* d1 = A1T + ((long)(b*512 + y) << 9) + ti*64 + cs;
    short* d2 = A2  + ((long)(b*512 + y) << 9) + ti*64 + cs;
    bfrag a0 = {o1[0],o1[1],o1[2],o1[3],o1[4],o1[5],o1[6],o1[7]};
    bfrag a1 = {o1[8],o1[9],o1[10],o1[11],o1[12],o1[13],o1[14],o1[15]};
    bfrag b0 = {o2[0],o2[1],o2[2],o2[3],o2[4],o2[5],o2[6],o2[7]};
    bfrag b1 = {o2[8],o2[9],o2[10],o2[11],o2[12],o2[13],o2[14],o2[15]};
    *(bfrag*)d1 = a0; *(bfrag*)(d1 + 8) = a1;
    *(bfrag*)d2 = b0; *(bfrag*)(d2 + 8) = b1;
  }
}

// folded + transposed gconv weights: WT[(m*out+o)*128 + feat]; W row index = feat*5 + m
__global__ void build_wcat(const void* W, const int* flg, short* WT, int f, int out) {
  const int f32 = *flg;
  const int i = blockIdx.x * 256 + threadIdx.x;
  if (i >= 5 * out * 128) return;
  const int feat = i & 127;
  const int mo = i >> 7;
  const int m = mo / out;
  const int o = mo - m * out;
  float v = 0.f;
  if (feat < f) {
    const long base = (long)feat * 5 * out;
    const float w0 = ldx(W, base + 0*out + o, f32);
    const float w1 = ldx(W, base + 1*out + o, f32);
    const float w2 = ldx(W, base + 2*out + o, f32);
    const float w3 = ldx(W, base + 3*out + o, f32);
    const float w4 = ldx(W, base + 4*out + o, f32);
    v = (m == 0) ? (w0 - w2) : (m == 1) ? (w1 - w4) : (m == 2) ? 2.f*w2
      : (m == 3) ? w3 : 2.f*w4;
  }
  WT[(long)mo * 128 + feat] = f2bf(v);
}

__global__ void build_fc1T(const void* W, const int* flg, short* WT) {
  const int f32 = *flg;
  const int i = blockIdx.x * 256 + threadIdx.x;  // 256*128
  const int o = i >> 7, k = i & 127;
  WT[i] = (k < 96) ? f2bf(ldx(W, (long)k*256 + o, f32)) : (short)0;
}
__global__ void build_fc2T(const void* W, const int* flg, short* WT) {
  const int f32 = *flg;
  const int i = blockIdx.x * 256 + threadIdx.x;  // 64*256
  const int o = i >> 8, k = i & 255;
  WT[i] = f2bf(ldx(W, (long)k*64 + o, f32));
}
__global__ void pack_hid(const void* hd, const int* flg, short* hp) {
  const int f32 = *flg;
  const int i = blockIdx.x * 256 + threadIdx.x;  // 16384*128
  const int row = i >> 7, k = i & 127;
  hp[i] = (k < 96) ? f2bf(ldx(hd, (long)row*96 + k, f32)) : (short)0;
}

// seed encoder t=0 hist cols into Xg0/Xc0
__global__ void seed_hist(const void* hist, const int* flg, short* Xg0, short* Xc0) {
  const int f32 = *flg;
  const int i = blockIdx.x * 256 + threadIdx.x;  // 32768
  const int row = i >> 1, c = i & 1;
  const short v = f2bf(ldx(hist, (long)(row >> 9)*12288 + (long)(row & 511)*2 + c, f32));
  Xg0[(long)row*128 + c] = v;
  Xc0[(long)row*128 + c] = v;
}

// enc->dec boundary: h += his; rewrite Xg0 (dec layout: col0=0, state cols 1..64) and
// Xg1 state cols 64..127; zero Xc0 col0.
__global__ void his_add(float* h0, float* h1, const short* his,
                        short* Xg0, short* Xc0, short* Xg1) {
  const int i = blockIdx.x * 256 + threadIdx.x;  // 1048576
  const int row = i >> 6, o = i & 63;
  const float v = bf2f(his[i]);
  const float a = h0[i] + v, b = h1[i] + v;
  h0[i] = a; h1[i] = b;
  Xg0[(long)row*128 + 1 + o]  = f2bf(a);
  Xg1[(long)row*128 + 64 + o] = f2bf(b);
  if (o == 0) { Xg0[(long)row*128] = 0; Xc0[(long)row*128] = 0; }
}

// wave-per-row projection: lane j handles h1[row*64+j] (coalesced), shuffle-reduce
__global__ void proj_k(const float* h1, const void* pw, const void* pb, const int* flg,
                       void* dout, short* Xg0, short* Xc0, int t) {
  const int f32 = *flg;
  const int row  = (blockIdx.x * 256 + threadIdx.x) >> 6;  // 0..16383 (grid 4096)
  const int lane = threadIdx.x & 63;
  float v = h1[((long)row << 6) + lane] * ldx(pw, lane, f32);
  for (int off = 32; off > 0; off >>= 1) v += __shfl_down(v, off, 64);
  if (lane == 0) {
    const float s = v + ldx(pb, 0, f32);
    if (f32) ((float*)dout)[row*12 + t] = s;
    else     ((short*)dout)[row*12 + t] = f2bf(s);
    const short o = f2bf(s);
    Xg0[(long)row*128] = o;
    Xc0[(long)row*128] = o;
  }
}

extern "C" void kernel_launch(void* const* d_in, const int* in_sizes, int n_in,
                              void* d_out, int out_size, void* d_ws, size_t ws_size,
                              hipStream_t stream) {
  (void)in_sizes; (void)n_in; (void)out_size;
  const void* hist   = d_in[0];
  const void* hidden = d_in[1];
  const void* adj    = d_in[2];
  const void* Wg[4] = {d_in[3], d_in[7],  d_in[11], d_in[15]};
  const void* bg[4] = {d_in[4], d_in[8],  d_in[12], d_in[16]};
  const void* Wc[4] = {d_in[5], d_in[9],  d_in[13], d_in[17]};
  const void* bc[4] = {d_in[6], d_in[10], d_in[14], d_in[18]};
  const void* projW = d_in[19];
  const void* projb = d_in[20];
  const void* fc1W  = d_in[21];
  const void* fc1b  = d_in[22];
  const void* fc2W  = d_in[23];
  const void* fc2b  = d_in[24];

  // ---- workspace layout: persistent + phase-union (lifetimes disjoint) ----
  char* wp = (char*)d_ws;
  auto alloc = [&](size_t bytes) { char* r = wp; wp += (bytes + 255) & ~(size_t)255; return r; };
  short* Pbig = (short*)alloc(32ull*512*2048*2);   // [A1 | A1^2 | A2A1 | A2^2A1], ld 2048
  float* ub   = (float*)alloc(16384ull*64*4);
  float* h0   = (float*)alloc(16384ull*64*4);
  float* h1   = (float*)alloc(16384ull*64*4);
  short* hisb = (short*)alloc(16384ull*64*2);
  short* wctg[4]; for (int i = 0; i < 4; i++) wctg[i] = (short*)alloc(640*128*2);
  short* wctc[4]; for (int i = 0; i < 4; i++) wctc[i] = (short*)alloc(320*128*2);
  float* rsi = (float*)alloc(16384*4);
  float* csi = (float*)alloc(16384*4);
  int*   flg = (int*)alloc(256);
  // phase-union region (phase lifetimes disjoint)
  char* ubase = wp;
  short* hidp = (short*)ubase;                         // phase0: 4,194,304 B
  short* mid  = (short*)(ubase + 4194304);             //          8,388,608 B
  short* fc1T = (short*)(ubase + 4194304 + 8388608);   //          65,536 B
  short* fc2T = (short*)(ubase + 4194304 + 8388608 + 65536);
  short* A1T  = (short*)ubase;                         // phase1: 16,777,216 B each
  short* A2   = (short*)(ubase + 16777216);
  short* P3T  = (short*)(ubase + 33554432);
  short* VTg  = (short*)ubase;                         // phase2: 20,971,520 B
  short* VTc  = (short*)(ubase + 20971520);            //         10,485,760 B
  short* Xg0  = (short*)(ubase + 31457280);            //          4,194,304 B each
  short* Xc0  = (short*)(ubase + 35651584);
  short* Xg1  = (short*)(ubase + 39845888);
  short* Xc1  = (short*)(ubase + 44040192);
  const size_t need = (size_t)(ubase - (char*)d_ws) + 48234496 + 2097152;
  if (ws_size < need) return;  // d_out stays zero: finite-absmax diagnostic signature

  detect_k<<<1, 64, 0, stream>>>((const short*)bg[0], flg);
  hipMemsetAsync(h0, 0, 16384ull*64*4, stream);
  hipMemsetAsync(h1, 0, 16384ull*64*4, stream);

  // ---- phase 0: weight prep + fc_his ----
  const int fdim[4] = {66, 128, 65, 128};  // enc0, enc1, dec0, dec1
  for (int i = 0; i < 4; i++) {
    build_wcat<<<320, 256, 0, stream>>>(Wg[i], flg, wctg[i], fdim[i], 128);
    build_wcat<<<160, 256, 0, stream>>>(Wc[i], flg, wctc[i], fdim[i], 64);
  }
  build_fc1T<<<128, 256, 0, stream>>>(fc1W, flg, fc1T);
  build_fc2T<<<64, 256, 0, stream>>>(fc2W, flg, fc2T);
  pack_hid<<<8192, 256, 0, stream>>>(hidden, flg, hidp);

  GP p;
  // fc_his: his = relu(relu(hid @ fc1 + b1) @ fc2 + b2)
  p = GP{}; p.A = hidp; p.lda = 128; p.BT = fc1T; p.ldbt = 128; p.K = 128;
  p.C = mid; p.ldc = 256; p.bias = fc1b; p.flg = flg;
  gemm_k<1,128,64,64,256,0,2><<<dim3(128, 4, 1), 256, 0, stream>>>(p);
  p = GP{}; p.A = mid; p.lda = 256; p.BT = fc2T; p.ldbt = 256; p.K = 256;
  p.C = hisb; p.ldc = 64; p.bias = fc2b; p.flg = flg;
  gemm_k<1,128,64,64,256,0,2><<<dim3(128, 1, 1), 256, 0, stream>>>(p);

  // ---- phase 1: diffusion matrices ----
  rowsum_inv<<<4096, 256, 0, stream>>>(adj, flg, rsi);
  colsum_inv<<<64, 256, 0, stream>>>(adj, flg, csi);
  build_a<<<dim3(8, 8, 32), 256, 0, stream>>>(adj, flg, rsi, csi, Pbig, A1T, A2);

  p = GP{}; p.A = Pbig; p.sA = 512*2048; p.lda = 2048;    // P2 = A1 @ A1
  p.BT = A1T; p.sBT = 512*512; p.ldbt = 512; p.K = 512;
  p.C = Pbig + 512; p.sC = 512*2048; p.ldc = 2048; p.flg = flg;
  gemm_k<0,128,64,64,256,0,2><<<dim3(4, 8, 32), 256, 0, stream>>>(p);
  p = GP{}; p.A = A2; p.sA = 512*512; p.lda = 512;        // P3 = A2 @ A1 (+ P3T)
  p.BT = A1T; p.sBT = 512*512; p.ldbt = 512; p.K = 512;
  p.C = Pbig + 1024; p.sC = 512*2048; p.ldc = 2048; p.CT = P3T; p.flg = flg;
  gemm_k<2,128,64,64,256,0,2><<<dim3(4, 8, 32), 256, 0, stream>>>(p);
  p = GP{}; p.A = A2; p.sA = 512*512; p.lda = 512;        // P4 = A2 @ P3
  p.BT = P3T; p.sBT = 512*512; p.ldbt = 512; p.K = 512;
  p.C = Pbig + 1536; p.sC = 512*2048; p.ldc = 2048; p.flg = flg;
  gemm_k<0,128,64,64,256,0,2><<<dim3(4, 8, 32), 256, 0, stream>>>(p);

  // ---- phase 2: RNN (persistent X buffers) ----
  hipMemsetAsync(Xg0, 0, 4ull*4194304, stream);  // Xg0,Xc0,Xg1,Xc1 contiguous
  seed_hist<<<128, 256, 0, stream>>>(hist, flg, Xg0, Xc0);

  // cell: wi weight idx, inpOff state col, hstate; EPI5 maintenance params
  auto run_cell = [&](int wi, int inpOff, float* hstate, short* XgL, short* XcL,
                      short* nxg, short* nxc, const void* hsrc, long hoff) {
    GP q;
    // GEMM1 gate: XgL(16384x128) @ WcatT -> VTg scatter (BN=128: A read 5x, 640 blocks)
    q = GP{}; q.A = XgL; q.lda = 128; q.BT = wctg[wi]; q.ldbt = 128; q.K = 128;
    q.CT = VTg; q.outDim = 128; q.oshift = 7; q.flg = flg;
    gemm_k<3,128,128,64,512,0,2><<<dim3(128, 5, 1), 512, 0, stream>>>(q);
    // GEMM2 gate: Pbig @ U (K=2048) -> sigmoid -> (r*h into XcL, u)
    // BM=64,BN=128: Pbig read once; 256 blocks, XCD swizzle, PIPE=4 (96KB LDS)
    q = GP{}; q.A = Pbig; q.sA = 512*2048; q.lda = 2048;
    q.BT = VTg + 512; q.sBT = 128*2560; q.ldbt = 2560; q.K = 2048;
    q.V0 = VTg; q.outDim = 128; q.bias = bg[wi]; q.flg = flg; q.mtiles = 8;
    q.h = hstate; q.hw = ub; q.xc = XcL; q.inpOff = inpOff;
    gemm_k<4,64,128,64,512,1,4><<<dim3(256, 1, 1), 512, 0, stream>>>(q);
    // GEMM1 cand
    q = GP{}; q.A = XcL; q.lda = 128; q.BT = wctc[wi]; q.ldbt = 128; q.K = 128;
    q.CT = VTc; q.outDim = 64; q.oshift = 6; q.flg = flg;
    gemm_k<3,128,64,64,256,0,2><<<dim3(128, 5, 1), 256, 0, stream>>>(q);
    // GEMM2 cand: tanh + h update + persistent-X maintenance
    // BM=64,BN=64: Pbig read once; 256 blocks, XCD swizzle, PIPE=4 (64KB LDS)
    q = GP{}; q.A = Pbig; q.sA = 512*2048; q.lda = 2048;
    q.BT = VTc + 512; q.sBT = 64*2560; q.ldbt = 2560; q.K = 2048;
    q.V0 = VTc; q.outDim = 64; q.bias = bc[wi]; q.flg = flg; q.mtiles = 8;
    q.h = hstate; q.hw = hstate; q.u = ub;
    q.xgs = XgL; q.xgsOff = inpOff; q.xch = XcL;
    q.nxg = nxg; q.nxc = nxc; q.hsrc = hsrc; q.hoff = hoff;
    gemm_k<5,64,64,64,256,1,4><<<dim3(256, 1, 1), 256, 0, stream>>>(q);
  };

  // encoder
  for (int t = 0; t < 12; t++) {
    run_cell(0, 2, h0, Xg0, Xc0, Xg1, Xc1,
             (t < 11) ? hist : nullptr, (long)(t + 1) * 1024);
    run_cell(1, 64, h1, Xg1, Xc1, nullptr, nullptr, nullptr, 0);
  }
  his_add<<<4096, 256, 0, stream>>>(h0, h1, hisb, Xg0, Xc0, Xg1);
  // decoder
  for (int t = 0; t < 12; t++) {
    run_cell(2, 1, h0, Xg0, Xc0, Xg1, Xc1, nullptr, 0);
    run_cell(3, 64, h1, Xg1, Xc1, nullptr, nullptr, nullptr, 0);
    proj_k<<<4096, 256, 0, stream>>>(h1, projW, projb, flg, d_out, Xg0, Xc0, t);
  }
}